// Round 6
// baseline (8268.483 us; speedup 1.0000x reference)
//
#include <hip/hip_runtime.h>
#include <hip/hip_bf16.h>
#include <cstdint>
#include <type_traits>

#define BATCH 8
#define SEQLEN 4096
#define D_MODEL 768
#define D_STATE 32
#define D_CONV 4
#define D_INNER 1536
#define DT_RANK 48
#define N_HIDDEN 2048
#define ACTION_BINS 256
#define MROWS (BATCH*SEQLEN)

typedef unsigned short bf16_t;

__device__ __forceinline__ float sigmoidf_(float x){ return 1.f/(1.f+__expf(-x)); }
__device__ __forceinline__ float bf2f(bf16_t u){
  unsigned int x = ((unsigned int)u) << 16; float f; __builtin_memcpy(&f,&x,4); return f;
}
__device__ __forceinline__ bf16_t f2bf(float f){
  unsigned int x; __builtin_memcpy(&x,&f,4);
  unsigned int r = x + 0x7FFFu + ((x>>16)&1u);   // round-to-nearest-even, finite inputs
  return (bf16_t)(r>>16);
}

// ---------------------------------------------------------------------------
// Mixed-storage SGEMM, fp32 compute. 128x128 tile, BK=8, 256 threads, 8x8
// microtile. A: [M,K] (TA = float | bf16_t), row stride lda. B: [K,N] fp32,
// row stride ldb. C: (TC = float | bf16_t), row stride N.
// EPI: 0 none, 1 bias+softplus, 2 bias+leakyrelu(0.01), 3 bias.
// Requires M%128==0, K%8==0, N%4==0 (all true here). N edge (112) handled.
// ---------------------------------------------------------------------------
template<typename TA, typename TC, int EPI>
__global__ __launch_bounds__(256)
void sgemm_k(const TA* __restrict__ A, int lda,
             const float* __restrict__ B, int ldb,
             const float* __restrict__ bias, TC* __restrict__ C,
             int M, int N, int K)
{
  constexpr int BM=128, BN=128, BK=8;
  __shared__ float As[BK][BM];   // transposed A tile
  __shared__ float Bs[BK][BN];
  const int tid = threadIdx.x;
  const int m0 = blockIdx.y*BM, n0 = blockIdx.x*BN;
  const int tx = tid & 15, ty = tid >> 4;
  const int ar = tid >> 1, akq = (tid & 1)*4;   // A load: row, k-quad
  const int bk = tid >> 5, bn = (tid & 31)*4;   // B load: k-row, n-quad
  float acc[8][8];
  #pragma unroll
  for (int i=0;i<8;i++)
    #pragma unroll
    for (int j=0;j<8;j++) acc[i][j]=0.f;

  for (int k0=0;k0<K;k0+=BK){
    if constexpr (std::is_same_v<TA,float>) {
      float4 av = *(const float4*)(A + (size_t)(m0+ar)*lda + k0 + akq);
      As[akq+0][ar]=av.x; As[akq+1][ar]=av.y; As[akq+2][ar]=av.z; As[akq+3][ar]=av.w;
    } else {
      ushort4 av = *(const ushort4*)(A + (size_t)(m0+ar)*lda + k0 + akq);
      As[akq+0][ar]=bf2f(av.x); As[akq+1][ar]=bf2f(av.y);
      As[akq+2][ar]=bf2f(av.z); As[akq+3][ar]=bf2f(av.w);
    }
    const float* Bp = B + (size_t)(k0+bk)*ldb;
    const int bcol = n0 + bn;
    float4 bv;
    if (bcol + 3 < N) {
      bv = *(const float4*)(Bp + bcol);
    } else {
      bv.x = bcol+0<N ? Bp[bcol+0] : 0.f;
      bv.y = bcol+1<N ? Bp[bcol+1] : 0.f;
      bv.z = bcol+2<N ? Bp[bcol+2] : 0.f;
      bv.w = bcol+3<N ? Bp[bcol+3] : 0.f;
    }
    *(float4*)&Bs[bk][bn] = bv;
    __syncthreads();
    #pragma unroll
    for (int k=0;k<BK;k++){
      float a[8], b[8];
      *(float4*)&a[0] = *(const float4*)&As[k][ty*8];
      *(float4*)&a[4] = *(const float4*)&As[k][ty*8+4];
      *(float4*)&b[0] = *(const float4*)&Bs[k][tx*8];
      *(float4*)&b[4] = *(const float4*)&Bs[k][tx*8+4];
      #pragma unroll
      for (int i=0;i<8;i++)
        #pragma unroll
        for (int j=0;j<8;j++)
          acc[i][j] = fmaf(a[i], b[j], acc[i][j]);
    }
    __syncthreads();
  }
  #pragma unroll
  for (int i=0;i<8;i++){
    const size_t row = (size_t)(m0 + ty*8 + i);
    TC* Cp = C + row*(size_t)N;
    #pragma unroll
    for (int j4=0;j4<2;j4++){
      const int col0 = n0 + tx*8 + j4*4;
      if (col0 < N){           // N%4==0 always, so 4-wide granularity is safe
        float t[4];
        #pragma unroll
        for (int j=0;j<4;j++){
          float u = acc[i][j4*4+j];
          const int c = col0 + j;
          if (EPI==1){ u += bias[c]; u = (u>20.f)? u : log1pf(__expf(u)); }
          else if (EPI==2){ u += bias[c]; u = (u>=0.f)? u : 0.01f*u; }
          else if (EPI==3){ u += bias[c]; }
          t[j]=u;
        }
        if constexpr (std::is_same_v<TC,float>) {
          float4 v; v.x=t[0]; v.y=t[1]; v.z=t[2]; v.w=t[3];
          *(float4*)(Cp + col0) = v;
        } else {
          ushort4 v; v.x=f2bf(t[0]); v.y=f2bf(t[1]); v.z=f2bf(t[2]); v.w=f2bf(t[3]);
          *(ushort4*)(Cp + col0) = v;
        }
      }
    }
  }
}

// ---------------------------------------------------------------------------
// Causal depthwise conv1d (width 4, pad-left 3) + bias + silu.
// xp: [CB,L,1536] bf16 (pre-conv x half). Out xc: [CB,L,1536] bf16.
// ---------------------------------------------------------------------------
__global__ __launch_bounds__(256)
void conv_silu_k(const bf16_t* __restrict__ xp, const float* __restrict__ cw,
                 const float* __restrict__ cb, bf16_t* __restrict__ xc)
{
  const int d = blockIdx.x*256 + threadIdx.x;
  const int l = blockIdx.y, b = blockIdx.z;
  float acc = cb[d];
  #pragma unroll
  for (int k=0;k<D_CONV;k++){
    const int ls = l - (D_CONV-1) + k;
    if (ls >= 0)
      acc = fmaf(cw[d*D_CONV+k], bf2f(xp[((size_t)(b*SEQLEN+ls))*D_INNER + d]), acc);
  }
  xc[((size_t)(b*SEQLEN+l))*D_INNER + d] = f2bf(acc * sigmoidf_(acc));
}

// ---------------------------------------------------------------------------
// Selective-scan. Block = 256 threads = 8 d-channels x 32 states.
// Grid (192, CB). Sequential over L, tiled by TL=32 in LDS (fp32 in LDS).
// Fused epilogue: yg = (y + x*D) * silu(z).
// ---------------------------------------------------------------------------
__global__ __launch_bounds__(256)
void scan_k(const bf16_t* __restrict__ dtb,   // [CB,L,1536] (softplus'd)
            const float*  __restrict__ proj,  // [CB,L,112] fp32 (B at 48, C at 80)
            const bf16_t* __restrict__ xc,    // [CB,L,1536]
            const bf16_t* __restrict__ zb,    // [CB,L,1536]
            const float*  __restrict__ A_log, // [1536,32]
            const float*  __restrict__ Dp,    // [1536]
            bf16_t* __restrict__ yg)          // [CB,L,1536]
{
  constexpr int TL = 32;
  __shared__ float s_dt[TL][8], s_x[TL][8], s_z[TL][8], s_y[TL][8];
  __shared__ float s_B[TL][32], s_C[TL][32];
  const int tid = threadIdx.x;
  const int n = tid & 31, dl = tid >> 5;       // state, local channel
  const int d0 = blockIdx.x * 8, b = blockIdx.y;
  const int d = d0 + dl;
  const float Adn = -expf(A_log[d*D_STATE + n]);
  const float Dd  = Dp[d];
  const int ll = tid >> 3, dd = tid & 7;       // cooperative-load mapping
  const int lb = tid >> 5;
  float h = 0.f;

  for (int l0 = 0; l0 < SEQLEN; l0 += TL){
    {
      const size_t r = (size_t)b*SEQLEN + l0 + ll;
      s_dt[ll][dd] = bf2f(dtb[r*D_INNER + d0 + dd]);
      s_x [ll][dd] = bf2f(xc [r*D_INNER + d0 + dd]);
      s_z [ll][dd] = bf2f(zb [r*D_INNER + d0 + dd]);
    }
    #pragma unroll
    for (int i=0;i<4;i++){
      const size_t rr = (size_t)b*SEQLEN + l0 + lb + i*8;
      s_B[lb+i*8][n] = proj[rr*(DT_RANK+2*D_STATE) + DT_RANK + n];
      s_C[lb+i*8][n] = proj[rr*(DT_RANK+2*D_STATE) + DT_RANK + D_STATE + n];
    }
    __syncthreads();
    for (int t=0;t<TL;t++){
      const float dtl = s_dt[t][dl];
      const float xv  = s_x[t][dl];
      const float dA  = __expf(dtl * Adn);
      h = fmaf(dA, h, (dtl*xv) * s_B[t][n]);
      float y = h * s_C[t][n];
      y += __shfl_xor(y,16); y += __shfl_xor(y,8);
      y += __shfl_xor(y,4);  y += __shfl_xor(y,2); y += __shfl_xor(y,1);
      if (n==0){
        const float zv = s_z[t][dl];
        s_y[t][dl] = (y + xv*Dd) * (zv * sigmoidf_(zv));
      }
    }
    __syncthreads();
    {
      const size_t r = (size_t)b*SEQLEN + l0 + ll;
      yg[r*D_INNER + d0 + dd] = f2bf(s_y[ll][dd]);
    }
    __syncthreads();
  }
}

// ---------------------------------------------------------------------------
extern "C" void kernel_launch(void* const* d_in, const int* in_sizes, int n_in,
                              void* d_out, int out_size, void* d_ws, size_t ws_size,
                              hipStream_t stream) {
  const float* x       = (const float*)d_in[0];
  const float* W_in    = (const float*)d_in[1];
  const float* conv_w  = (const float*)d_in[2];
  const float* conv_b  = (const float*)d_in[3];
  const float* W_xproj = (const float*)d_in[4];
  const float* W_dt    = (const float*)d_in[5];
  const float* b_dt    = (const float*)d_in[6];
  const float* A_log   = (const float*)d_in[7];
  const float* Dp      = (const float*)d_in[8];
  const float* W_out   = (const float*)d_in[9];
  const float* W_ff1   = (const float*)d_in[10];
  const float* b_ff1   = (const float*)d_in[11];
  const float* W_ff2   = (const float*)d_in[12];
  const float* b_ff2   = (const float*)d_in[13];
  float* out = (float*)d_out;

  // ---- adaptive batch chunking --------------------------------------------
  // Per-batch workspace (bytes): 4 x bf16[4096,1536] (A_pre|Z|XC|YG) +
  // fp32[4096,112] (PROJ) = 52,166,656. One region reused serially per chunk.
  const size_t SZ16_1 = (size_t)SEQLEN * D_INNER * 2;             // 12,582,912
  const size_t PROJ_1 = (size_t)SEQLEN * (DT_RANK+2*D_STATE) * 4; //  1,835,008
  const size_t PER_B  = 4*SZ16_1 + PROJ_1;                        // 52,166,656
  int CB = 0;
  for (int cb = BATCH; cb >= 1; cb >>= 1)
    if ((size_t)cb * PER_B <= ws_size) { CB = cb; break; }
  if (CB == 0) return;   // ws too small even for one batch -> clean diagnostic

  const size_t SZ16 = (size_t)CB * SZ16_1;
  char* wsb = (char*)d_ws;
  bf16_t* A_pre = (bf16_t*)wsb;                 // -> DT after conv
  bf16_t* Z     = (bf16_t*)(wsb +   SZ16);      // -> H1 after scan
  bf16_t* XC    = (bf16_t*)(wsb + 2*SZ16);      // -> H2 (+PROJ+YG) after GEMM6
  float*  PROJ  = (float*) (wsb + 3*SZ16);
  bf16_t* YG    = (bf16_t*)(wsb + 3*SZ16 + (size_t)CB*PROJ_1);
  bf16_t* DT    = A_pre;
  bf16_t* H1    = Z;
  bf16_t* H2    = XC;

  const int Mc = CB * SEQLEN;          // rows per chunk
  const int nchunks = BATCH / CB;
  dim3 blk(256);

  for (int c = 0; c < nchunks; ++c) {
    const float* xc_in = x   + (size_t)c*Mc*D_MODEL;
    float*       out_c = out + (size_t)c*Mc*ACTION_BINS;

    // 1a) A_pre = x @ W_in[:, :1536]
    sgemm_k<float,bf16_t,0><<<dim3(D_INNER/128, Mc/128), blk, 0, stream>>>(
        xc_in, D_MODEL, W_in, 2*D_INNER, nullptr, A_pre, Mc, D_INNER, D_MODEL);
    // 1b) Z = x @ W_in[:, 1536:]
    sgemm_k<float,bf16_t,0><<<dim3(D_INNER/128, Mc/128), blk, 0, stream>>>(
        xc_in, D_MODEL, W_in + D_INNER, 2*D_INNER, nullptr, Z, Mc, D_INNER, D_MODEL);

    // 2) XC = silu(causal_conv(A_pre) + conv_b)
    conv_silu_k<<<dim3(D_INNER/256, SEQLEN, CB), blk, 0, stream>>>(A_pre, conv_w, conv_b, XC);

    // 3) PROJ = XC @ W_xproj            [Mc,1536]@[1536,112] -> fp32
    sgemm_k<bf16_t,float,0><<<dim3(1, Mc/128), blk, 0, stream>>>(
        XC, D_INNER, W_xproj, DT_RANK+2*D_STATE, nullptr, PROJ, Mc, DT_RANK+2*D_STATE, D_INNER);

    // 4) DT = softplus(PROJ[:, :48] @ W_dt + b_dt)   [Mc,48]@[48,1536]
    sgemm_k<float,bf16_t,1><<<dim3(D_INNER/128, Mc/128), blk, 0, stream>>>(
        PROJ, DT_RANK+2*D_STATE, W_dt, D_INNER, b_dt, DT, Mc, D_INNER, DT_RANK);

    // 5) selective scan + skip + gate -> YG
    scan_k<<<dim3(D_INNER/8, CB), blk, 0, stream>>>(DT, PROJ, XC, Z, A_log, Dp, YG);

    // 6) H1 = YG @ W_out                [Mc,1536]@[1536,768]
    sgemm_k<bf16_t,bf16_t,0><<<dim3(D_MODEL/128, Mc/128), blk, 0, stream>>>(
        YG, D_INNER, W_out, D_MODEL, nullptr, H1, Mc, D_MODEL, D_INNER);

    // 7) H2 = leaky_relu(H1 @ W_ff1 + b_ff1)  [Mc,768]@[768,2048]
    sgemm_k<bf16_t,bf16_t,2><<<dim3(N_HIDDEN/128, Mc/128), blk, 0, stream>>>(
        H1, D_MODEL, W_ff1, N_HIDDEN, b_ff1, H2, Mc, N_HIDDEN, D_MODEL);

    // 8) out = H2 @ W_ff2 + b_ff2       [Mc,2048]@[2048,256]
    sgemm_k<bf16_t,float,3><<<dim3(ACTION_BINS/128, Mc/128), blk, 0, stream>>>(
        H2, N_HIDDEN, W_ff2, ACTION_BINS, b_ff2, out_c, Mc, ACTION_BINS, N_HIDDEN);
  }
}

// Round 8
// 4292.937 us; speedup vs baseline: 1.9261x; 1.9261x over previous
//
#include <hip/hip_runtime.h>
#include <hip/hip_bf16.h>
#include <cstdint>
#include <type_traits>

#define BATCH 8
#define SEQLEN 4096
#define D_MODEL 768
#define D_STATE 32
#define D_CONV 4
#define D_INNER 1536
#define DT_RANK 48
#define N_HIDDEN 2048
#define ACTION_BINS 256
#define MROWS (BATCH*SEQLEN)

typedef unsigned short bf16_t;
typedef __attribute__((ext_vector_type(8))) short s8v;   // 8 bf16 (4 VGPRs)
typedef __attribute__((ext_vector_type(4))) float f4v;   // 4 fp32 acc

__device__ __forceinline__ float sigmoidf_(float x){ return 1.f/(1.f+__expf(-x)); }
__device__ __forceinline__ float bf2f(bf16_t u){
  unsigned int x = ((unsigned int)u) << 16; float f; __builtin_memcpy(&f,&x,4); return f;
}
__device__ __forceinline__ bf16_t f2bf(float f){
  unsigned int x; __builtin_memcpy(&x,&f,4);
  unsigned int r = x + 0x7FFFu + ((x>>16)&1u);   // RNE, finite inputs
  return (bf16_t)(r>>16);
}
__device__ __forceinline__ void gload_lds16(const bf16_t* g, short* l){
  __builtin_amdgcn_global_load_lds(
      (const __attribute__((address_space(1))) void*)g,
      (__attribute__((address_space(3))) void*)l, 16, 0, 0);
}

// ---------------------------------------------------------------------------
// BF16 MFMA GEMM (m97-style): 128x128 tile, BK=32, 256 thr = 4 waves (2x2),
// each wave 64x64 = 4x4 frags of 16x16x32. A [M,K] bf16 (lda=K), Bt [N,K]
// bf16 (B transposed). global_load_lds width-16 staging, single LDS buffer.
// EPI: 0 none, 2 bias+leakyrelu(0.01), 3 bias. Requires M%128==N%128==K%32==0.
// ---------------------------------------------------------------------------
template<typename TC, int EPI>
__global__ __launch_bounds__(256)
void mgemm_k(const bf16_t* __restrict__ A, int lda,
             const bf16_t* __restrict__ Bt,
             const float* __restrict__ bias, TC* __restrict__ C,
             int M, int N, int K)
{
  __shared__ short As[128*32];
  __shared__ short Bs[128*32];
  const int tid = threadIdx.x;
  const int l = tid & 63, w = tid >> 6;
  const int m0 = blockIdx.y*128, n0 = blockIdx.x*128;
  const int wr = w >> 1, wc = w & 1;           // wave 2x2 -> 64x64 out
  f4v acc[4][4];
  #pragma unroll
  for (int i=0;i<4;i++)
    #pragma unroll
    for (int j=0;j<4;j++) acc[i][j] = (f4v){0.f,0.f,0.f,0.f};

  // staging: wave w covers rows 32w..32w+31 of each tile, 2x 1KB chunks.
  const int srow = 32*w + (l>>2);              // chunk0 row (chunk1 = +16)
  const int skch = (l&3)*8;                    // k offset (8 bf16 = 16B)
  short* asb = &As[(32*w)*32];
  short* bsb = &Bs[(32*w)*32];
  const bf16_t* Ab = A  + (size_t)(m0+srow)*lda + skch;
  const bf16_t* Bb = Bt + (size_t)(n0+srow)*lda + skch;   // note: ldb == lda == K
  const int fr = l & 15, fg = (l >> 4)*8;      // frag row/col, k-group

  for (int k0 = 0; k0 < K; k0 += 32){
    gload_lds16(Ab + k0,            asb);
    gload_lds16(Ab + k0 + 16*lda,   asb + 16*32);
    gload_lds16(Bb + k0,            bsb);
    gload_lds16(Bb + k0 + 16*lda,   bsb + 16*32);
    __syncthreads();                            // drains vmcnt -> LDS valid
    s8v a[4], b[4];
    #pragma unroll
    for (int mi=0;mi<4;mi++)
      a[mi] = *(const s8v*)&As[(wr*64 + mi*16 + fr)*32 + fg];
    #pragma unroll
    for (int ni=0;ni<4;ni++)
      b[ni] = *(const s8v*)&Bs[(wc*64 + ni*16 + fr)*32 + fg];
    #pragma unroll
    for (int mi=0;mi<4;mi++)
      #pragma unroll
      for (int ni=0;ni<4;ni++)
        acc[mi][ni] = __builtin_amdgcn_mfma_f32_16x16x32_bf16(a[mi], b[ni], acc[mi][ni], 0, 0, 0);
    __syncthreads();                            // before next-stage overwrite
  }

  // epilogue: D frag (mi,ni) reg r -> row = wr*64+mi*16+(l>>4)*4+r, col = wc*64+ni*16+(l&15)
  #pragma unroll
  for (int mi=0;mi<4;mi++){
    #pragma unroll
    for (int ni=0;ni<4;ni++){
      const int col = n0 + wc*64 + ni*16 + fr;
      float bv = (EPI==0) ? 0.f : bias[col];
      #pragma unroll
      for (int r=0;r<4;r++){
        const int row = m0 + wr*64 + mi*16 + (l>>4)*4 + r;
        float u = acc[mi][ni][r];
        if (EPI==2){ u += bv; u = (u>=0.f)? u : 0.01f*u; }
        else if (EPI==3){ u += bv; }
        if constexpr (std::is_same_v<TC,float>) C[(size_t)row*N + col] = u;
        else                                    C[(size_t)row*N + col] = f2bf(u);
      }
    }
  }
}

// ---------------------------------------------------------------------------
// fp32-compute SGEMM (kept for the two small GEMMs: N=112 and K=48).
// ---------------------------------------------------------------------------
template<typename TA, typename TC, int EPI>
__global__ __launch_bounds__(256)
void sgemm_k(const TA* __restrict__ A, int lda,
             const float* __restrict__ B, int ldb,
             const float* __restrict__ bias, TC* __restrict__ C,
             int M, int N, int K)
{
  constexpr int BM=128, BN=128, BK=8;
  __shared__ float As[BK][BM];
  __shared__ float Bs[BK][BN];
  const int tid = threadIdx.x;
  const int m0 = blockIdx.y*BM, n0 = blockIdx.x*BN;
  const int tx = tid & 15, ty = tid >> 4;
  const int ar = tid >> 1, akq = (tid & 1)*4;
  const int bk = tid >> 5, bn = (tid & 31)*4;
  float acc[8][8];
  #pragma unroll
  for (int i=0;i<8;i++)
    #pragma unroll
    for (int j=0;j<8;j++) acc[i][j]=0.f;

  for (int k0=0;k0<K;k0+=BK){
    if constexpr (std::is_same_v<TA,float>) {
      float4 av = *(const float4*)(A + (size_t)(m0+ar)*lda + k0 + akq);
      As[akq+0][ar]=av.x; As[akq+1][ar]=av.y; As[akq+2][ar]=av.z; As[akq+3][ar]=av.w;
    } else {
      ushort4 av = *(const ushort4*)(A + (size_t)(m0+ar)*lda + k0 + akq);
      As[akq+0][ar]=bf2f(av.x); As[akq+1][ar]=bf2f(av.y);
      As[akq+2][ar]=bf2f(av.z); As[akq+3][ar]=bf2f(av.w);
    }
    const float* Bp = B + (size_t)(k0+bk)*ldb;
    const int bcol = n0 + bn;
    float4 bv;
    if (bcol + 3 < N) {
      bv = *(const float4*)(Bp + bcol);
    } else {
      bv.x = bcol+0<N ? Bp[bcol+0] : 0.f;
      bv.y = bcol+1<N ? Bp[bcol+1] : 0.f;
      bv.z = bcol+2<N ? Bp[bcol+2] : 0.f;
      bv.w = bcol+3<N ? Bp[bcol+3] : 0.f;
    }
    *(float4*)&Bs[bk][bn] = bv;
    __syncthreads();
    #pragma unroll
    for (int k=0;k<BK;k++){
      float a[8], b[8];
      *(float4*)&a[0] = *(const float4*)&As[k][ty*8];
      *(float4*)&a[4] = *(const float4*)&As[k][ty*8+4];
      *(float4*)&b[0] = *(const float4*)&Bs[k][tx*8];
      *(float4*)&b[4] = *(const float4*)&Bs[k][tx*8+4];
      #pragma unroll
      for (int i=0;i<8;i++)
        #pragma unroll
        for (int j=0;j<8;j++)
          acc[i][j] = fmaf(a[i], b[j], acc[i][j]);
    }
    __syncthreads();
  }
  #pragma unroll
  for (int i=0;i<8;i++){
    const size_t row = (size_t)(m0 + ty*8 + i);
    TC* Cp = C + row*(size_t)N;
    #pragma unroll
    for (int j4=0;j4<2;j4++){
      const int col0 = n0 + tx*8 + j4*4;
      if (col0 < N){
        float t[4];
        #pragma unroll
        for (int j=0;j<4;j++){
          float u = acc[i][j4*4+j];
          const int c = col0 + j;
          if (EPI==1){ u += bias[c]; u = (u>20.f)? u : log1pf(__expf(u)); }
          else if (EPI==2){ u += bias[c]; u = (u>=0.f)? u : 0.01f*u; }
          else if (EPI==3){ u += bias[c]; }
          t[j]=u;
        }
        if constexpr (std::is_same_v<TC,float>) {
          float4 v; v.x=t[0]; v.y=t[1]; v.z=t[2]; v.w=t[3];
          *(float4*)(Cp + col0) = v;
        } else {
          ushort4 v; v.x=f2bf(t[0]); v.y=f2bf(t[1]); v.z=f2bf(t[2]); v.w=f2bf(t[3]);
          *(ushort4*)(Cp + col0) = v;
        }
      }
    }
  }
}

// ---------------------------------------------------------------------------
// weight transpose + fp32->bf16:  W [K][N] -> Wt [N][K]
// ---------------------------------------------------------------------------
__global__ __launch_bounds__(256)
void convert_wt_k(const float* __restrict__ W, bf16_t* __restrict__ Wt, int K, int N)
{
  const int idx = blockIdx.x*256 + threadIdx.x;
  if (idx < K*N){
    const int k = idx / N, n = idx % N;
    Wt[(size_t)n*K + k] = f2bf(W[idx]);
  }
}

// x fp32 -> bf16 (vectorized 4-wide)
__global__ __launch_bounds__(256)
void convert_x_k(const float* __restrict__ x, bf16_t* __restrict__ xb, int n4)
{
  const int i = blockIdx.x*256 + threadIdx.x;
  if (i < n4){
    float4 v = *(const float4*)(x + (size_t)i*4);
    ushort4 o; o.x=f2bf(v.x); o.y=f2bf(v.y); o.z=f2bf(v.z); o.w=f2bf(v.w);
    *(ushort4*)(xb + (size_t)i*4) = o;
  }
}

// ---------------------------------------------------------------------------
// Causal depthwise conv1d (width 4, pad-left 3) + bias + silu.
// ---------------------------------------------------------------------------
__global__ __launch_bounds__(256)
void conv_silu_k(const bf16_t* __restrict__ xp, const float* __restrict__ cw,
                 const float* __restrict__ cb, bf16_t* __restrict__ xc)
{
  const int d = blockIdx.x*256 + threadIdx.x;
  const int l = blockIdx.y, b = blockIdx.z;
  float acc = cb[d];
  #pragma unroll
  for (int k=0;k<D_CONV;k++){
    const int ls = l - (D_CONV-1) + k;
    if (ls >= 0)
      acc = fmaf(cw[d*D_CONV+k], bf2f(xp[((size_t)(b*SEQLEN+ls))*D_INNER + d]), acc);
  }
  xc[((size_t)(b*SEQLEN+l))*D_INNER + d] = f2bf(acc * sigmoidf_(acc));
}

// ---------------------------------------------------------------------------
// Selective-scan (unchanged this round; next optimization target).
// ---------------------------------------------------------------------------
__global__ __launch_bounds__(256)
void scan_k(const bf16_t* __restrict__ dtb,
            const float*  __restrict__ proj,
            const bf16_t* __restrict__ xc,
            const bf16_t* __restrict__ zb,
            const float*  __restrict__ A_log,
            const float*  __restrict__ Dp,
            bf16_t* __restrict__ yg)
{
  constexpr int TL = 32;
  __shared__ float s_dt[TL][8], s_x[TL][8], s_z[TL][8], s_y[TL][8];
  __shared__ float s_B[TL][32], s_C[TL][32];
  const int tid = threadIdx.x;
  const int n = tid & 31, dl = tid >> 5;
  const int d0 = blockIdx.x * 8, b = blockIdx.y;
  const int d = d0 + dl;
  const float Adn = -expf(A_log[d*D_STATE + n]);
  const float Dd  = Dp[d];
  const int ll = tid >> 3, dd = tid & 7;
  const int lb = tid >> 5;
  float h = 0.f;

  for (int l0 = 0; l0 < SEQLEN; l0 += TL){
    {
      const size_t r = (size_t)b*SEQLEN + l0 + ll;
      s_dt[ll][dd] = bf2f(dtb[r*D_INNER + d0 + dd]);
      s_x [ll][dd] = bf2f(xc [r*D_INNER + d0 + dd]);
      s_z [ll][dd] = bf2f(zb [r*D_INNER + d0 + dd]);
    }
    #pragma unroll
    for (int i=0;i<4;i++){
      const size_t rr = (size_t)b*SEQLEN + l0 + lb + i*8;
      s_B[lb+i*8][n] = proj[rr*(DT_RANK+2*D_STATE) + DT_RANK + n];
      s_C[lb+i*8][n] = proj[rr*(DT_RANK+2*D_STATE) + DT_RANK + D_STATE + n];
    }
    __syncthreads();
    for (int t=0;t<TL;t++){
      const float dtl = s_dt[t][dl];
      const float xv  = s_x[t][dl];
      const float dA  = __expf(dtl * Adn);
      h = fmaf(dA, h, (dtl*xv) * s_B[t][n]);
      float y = h * s_C[t][n];
      y += __shfl_xor(y,16); y += __shfl_xor(y,8);
      y += __shfl_xor(y,4);  y += __shfl_xor(y,2); y += __shfl_xor(y,1);
      if (n==0){
        const float zv = s_z[t][dl];
        s_y[t][dl] = (y + xv*Dd) * (zv * sigmoidf_(zv));
      }
    }
    __syncthreads();
    {
      const size_t r = (size_t)b*SEQLEN + l0 + ll;
      yg[r*D_INNER + d0 + dd] = f2bf(s_y[ll][dd]);
    }
    __syncthreads();
  }
}

// ---------------------------------------------------------------------------
extern "C" void kernel_launch(void* const* d_in, const int* in_sizes, int n_in,
                              void* d_out, int out_size, void* d_ws, size_t ws_size,
                              hipStream_t stream) {
  const float* x       = (const float*)d_in[0];
  const float* W_in    = (const float*)d_in[1];
  const float* conv_w  = (const float*)d_in[2];
  const float* conv_b  = (const float*)d_in[3];
  const float* W_xproj = (const float*)d_in[4];
  const float* W_dt    = (const float*)d_in[5];
  const float* b_dt    = (const float*)d_in[6];
  const float* A_log   = (const float*)d_in[7];
  const float* Dp      = (const float*)d_in[8];
  const float* W_out   = (const float*)d_in[9];
  const float* W_ff1   = (const float*)d_in[10];
  const float* b_ff1   = (const float*)d_in[11];
  const float* W_ff2   = (const float*)d_in[12];
  const float* b_ff2   = (const float*)d_in[13];
  float* out = (float*)d_out;

  // ---- transposed-bf16 weight sizes (elements) ----------------------------
  const size_t E_WIN  = (size_t)D_MODEL*2*D_INNER;   // 2.36M  (Wt: [3072][768])
  const size_t E_WOUT = (size_t)D_INNER*D_MODEL;     // 1.18M  (Wt: [768][1536])
  const size_t E_WF1  = (size_t)D_MODEL*N_HIDDEN;    // 1.57M  (Wt: [2048][768])
  const size_t E_WF2  = (size_t)N_HIDDEN*ACTION_BINS;// 0.52M  (Wt: [256][2048])
  const size_t WT_BYTES = 2*(E_WIN + E_WOUT + E_WF1 + E_WF2);  // 11.3 MB

  // ---- adaptive batch chunking --------------------------------------------
  const size_t SZ16_1 = (size_t)SEQLEN * D_INNER * 2;             // 12,582,912
  const size_t PROJ_1 = (size_t)SEQLEN * (DT_RANK+2*D_STATE) * 4; //  1,835,008
  const size_t PER_B  = 4*SZ16_1 + PROJ_1;                        // 52,166,656
  int CB = 0;
  for (int cb = BATCH; cb >= 1; cb >>= 1)
    if ((size_t)cb * PER_B + WT_BYTES <= ws_size) { CB = cb; break; }
  if (CB == 0) return;

  const size_t SZ16 = (size_t)CB * SZ16_1;
  char* wsb = (char*)d_ws;
  bf16_t* A_pre = (bf16_t*)wsb;                 // -> DT after conv
  bf16_t* Z     = (bf16_t*)(wsb +   SZ16);      // -> H1 after scan
  bf16_t* XC    = (bf16_t*)(wsb + 2*SZ16);      // -> H2 (+PROJ+YG) after GEMM6
  float*  PROJ  = (float*) (wsb + 3*SZ16);
  bf16_t* YG    = (bf16_t*)(wsb + 3*SZ16 + (size_t)CB*PROJ_1);
  bf16_t* DT    = A_pre;
  bf16_t* H1    = Z;
  bf16_t* H2    = XC;
  bf16_t* XB    = YG;        // x-as-bf16 lives in YG slot (dead before scan)

  bf16_t* WT    = (bf16_t*)(wsb + (size_t)CB * PER_B);
  bf16_t* WT_in  = WT;
  bf16_t* WT_out = WT_in  + E_WIN;
  bf16_t* WT_ff1 = WT_out + E_WOUT;
  bf16_t* WT_ff2 = WT_ff1 + E_WF1;

  const int Mc = CB * SEQLEN;
  const int nchunks = BATCH / CB;
  dim3 blk(256);

  // ---- once per call: weights -> bf16, transposed -------------------------
  convert_wt_k<<<dim3((int)((E_WIN +255)/256)), blk, 0, stream>>>(W_in,  WT_in,  D_MODEL, 2*D_INNER);
  convert_wt_k<<<dim3((int)((E_WOUT+255)/256)), blk, 0, stream>>>(W_out, WT_out, D_INNER, D_MODEL);
  convert_wt_k<<<dim3((int)((E_WF1 +255)/256)), blk, 0, stream>>>(W_ff1, WT_ff1, D_MODEL, N_HIDDEN);
  convert_wt_k<<<dim3((int)((E_WF2 +255)/256)), blk, 0, stream>>>(W_ff2, WT_ff2, N_HIDDEN, ACTION_BINS);

  for (int c = 0; c < nchunks; ++c) {
    const float* xc_in = x   + (size_t)c*Mc*D_MODEL;
    float*       out_c = out + (size_t)c*Mc*ACTION_BINS;

    // 0) XB = bf16(x chunk)    (lives in YG region; dead before scan writes YG)
    convert_x_k<<<dim3((Mc*D_MODEL/4 + 255)/256), blk, 0, stream>>>(xc_in, XB, Mc*D_MODEL/4);

    // 1a) A_pre = XB @ W_in[:, :1536]      (MFMA)
    mgemm_k<bf16_t,0><<<dim3(D_INNER/128, Mc/128), blk, 0, stream>>>(
        XB, D_MODEL, WT_in, nullptr, A_pre, Mc, D_INNER, D_MODEL);
    // 1b) Z = XB @ W_in[:, 1536:]          (MFMA)
    mgemm_k<bf16_t,0><<<dim3(D_INNER/128, Mc/128), blk, 0, stream>>>(
        XB, D_MODEL, WT_in + (size_t)D_INNER*D_MODEL, nullptr, Z, Mc, D_INNER, D_MODEL);

    // 2) XC = silu(causal_conv(A_pre) + conv_b)
    conv_silu_k<<<dim3(D_INNER/256, SEQLEN, CB), blk, 0, stream>>>(A_pre, conv_w, conv_b, XC);

    // 3) PROJ = XC @ W_xproj               [Mc,1536]@[1536,112] fp32 (N=112 edge)
    sgemm_k<bf16_t,float,0><<<dim3(1, Mc/128), blk, 0, stream>>>(
        XC, D_INNER, W_xproj, DT_RANK+2*D_STATE, nullptr, PROJ, Mc, DT_RANK+2*D_STATE, D_INNER);

    // 4) DT = softplus(PROJ[:, :48] @ W_dt + b_dt)   [Mc,48]@[48,1536] fp32 (K=48)
    sgemm_k<float,bf16_t,1><<<dim3(D_INNER/128, Mc/128), blk, 0, stream>>>(
        PROJ, DT_RANK+2*D_STATE, W_dt, D_INNER, b_dt, DT, Mc, D_INNER, DT_RANK);

    // 5) selective scan + skip + gate -> YG (overwrites XB; XB dead)
    scan_k<<<dim3(D_INNER/8, CB), blk, 0, stream>>>(DT, PROJ, XC, Z, A_log, Dp, YG);

    // 6) H1 = YG @ W_out                   (MFMA)
    mgemm_k<bf16_t,0><<<dim3(D_MODEL/128, Mc/128), blk, 0, stream>>>(
        YG, D_INNER, WT_out, nullptr, H1, Mc, D_MODEL, D_INNER);

    // 7) H2 = leaky_relu(H1 @ W_ff1 + b_ff1)   (MFMA)
    mgemm_k<bf16_t,2><<<dim3(N_HIDDEN/128, Mc/128), blk, 0, stream>>>(
        H1, D_MODEL, WT_ff1, b_ff1, H2, Mc, N_HIDDEN, D_MODEL);

    // 8) out = H2 @ W_ff2 + b_ff2              (MFMA, fp32 out)
    mgemm_k<float,3><<<dim3(ACTION_BINS/128, Mc/128), blk, 0, stream>>>(
        H2, N_HIDDEN, WT_ff2, b_ff2, out_c, Mc, ACTION_BINS, N_HIDDEN);
  }
}

// Round 10
// 3596.601 us; speedup vs baseline: 2.2990x; 1.1936x over previous
//
#include <hip/hip_runtime.h>
#include <hip/hip_bf16.h>
#include <cstdint>
#include <type_traits>

#define BATCH 8
#define SEQLEN 4096
#define D_MODEL 768
#define D_STATE 32
#define D_CONV 4
#define D_INNER 1536
#define DT_RANK 48
#define N_HIDDEN 2048
#define ACTION_BINS 256
#define MROWS (BATCH*SEQLEN)

typedef unsigned short bf16_t;
typedef __attribute__((ext_vector_type(8))) short s8v;   // 8 bf16 (4 VGPRs)
typedef __attribute__((ext_vector_type(4))) float f4v;   // 4 fp32 acc

__device__ __forceinline__ float sigmoidf_(float x){ return 1.f/(1.f+__expf(-x)); }
__device__ __forceinline__ float bf2f(bf16_t u){
  unsigned int x = ((unsigned int)u) << 16; float f; __builtin_memcpy(&f,&x,4); return f;
}
__device__ __forceinline__ bf16_t f2bf(float f){
  unsigned int x; __builtin_memcpy(&x,&f,4);
  unsigned int r = x + 0x7FFFu + ((x>>16)&1u);   // RNE, finite inputs
  return (bf16_t)(r>>16);
}
__device__ __forceinline__ void gload_lds16(const bf16_t* g, short* l){
  __builtin_amdgcn_global_load_lds(
      (const __attribute__((address_space(1))) void*)g,
      (__attribute__((address_space(3))) void*)l, 16, 0, 0);
}
// cross-lane add via DPP (VALU rate, no DS traffic). bound_ctrl=1 -> OOB reads 0.
// CTRL must be a compile-time constant (builtin requirement).
template<int CTRL>
__device__ __forceinline__ float dpp_add(float x){
  int yi = __builtin_amdgcn_update_dpp(0, __builtin_bit_cast(int, x), CTRL, 0xF, 0xF, true);
  return x + __builtin_bit_cast(float, yi);
}

// ---------------------------------------------------------------------------
// BF16 MFMA GEMM (m97-style): 128x128 tile, BK=32, 256 thr = 4 waves (2x2),
// each wave 64x64 = 4x4 frags of 16x16x32. A [M,K] bf16 (lda=K), Bt [N,K]
// bf16 (B transposed). global_load_lds width-16 staging, single LDS buffer.
// EPI: 0 none, 2 bias+leakyrelu(0.01), 3 bias. Requires M%128==N%128==K%32==0.
// ---------------------------------------------------------------------------
template<typename TC, int EPI>
__global__ __launch_bounds__(256)
void mgemm_k(const bf16_t* __restrict__ A, int lda,
             const bf16_t* __restrict__ Bt,
             const float* __restrict__ bias, TC* __restrict__ C,
             int M, int N, int K)
{
  __shared__ short As[128*32];
  __shared__ short Bs[128*32];
  const int tid = threadIdx.x;
  const int l = tid & 63, w = tid >> 6;
  const int m0 = blockIdx.y*128, n0 = blockIdx.x*128;
  const int wr = w >> 1, wc = w & 1;           // wave 2x2 -> 64x64 out
  f4v acc[4][4];
  #pragma unroll
  for (int i=0;i<4;i++)
    #pragma unroll
    for (int j=0;j<4;j++) acc[i][j] = (f4v){0.f,0.f,0.f,0.f};

  // staging: wave w covers rows 32w..32w+31 of each tile, 2x 1KB chunks.
  const int srow = 32*w + (l>>2);              // chunk0 row (chunk1 = +16)
  const int skch = (l&3)*8;                    // k offset (8 bf16 = 16B)
  short* asb = &As[(32*w)*32];
  short* bsb = &Bs[(32*w)*32];
  const bf16_t* Ab = A  + (size_t)(m0+srow)*lda + skch;
  const bf16_t* Bb = Bt + (size_t)(n0+srow)*lda + skch;   // note: ldb == lda == K
  const int fr = l & 15, fg = (l >> 4)*8;      // frag row/col, k-group

  for (int k0 = 0; k0 < K; k0 += 32){
    gload_lds16(Ab + k0,            asb);
    gload_lds16(Ab + k0 + 16*lda,   asb + 16*32);
    gload_lds16(Bb + k0,            bsb);
    gload_lds16(Bb + k0 + 16*lda,   bsb + 16*32);
    __syncthreads();                            // drains vmcnt -> LDS valid
    s8v a[4], b[4];
    #pragma unroll
    for (int mi=0;mi<4;mi++)
      a[mi] = *(const s8v*)&As[(wr*64 + mi*16 + fr)*32 + fg];
    #pragma unroll
    for (int ni=0;ni<4;ni++)
      b[ni] = *(const s8v*)&Bs[(wc*64 + ni*16 + fr)*32 + fg];
    #pragma unroll
    for (int mi=0;mi<4;mi++)
      #pragma unroll
      for (int ni=0;ni<4;ni++)
        acc[mi][ni] = __builtin_amdgcn_mfma_f32_16x16x32_bf16(a[mi], b[ni], acc[mi][ni], 0, 0, 0);
    __syncthreads();                            // before next-stage overwrite
  }

  // epilogue: D frag (mi,ni) reg r -> row = wr*64+mi*16+(l>>4)*4+r, col = wc*64+ni*16+(l&15)
  #pragma unroll
  for (int mi=0;mi<4;mi++){
    #pragma unroll
    for (int ni=0;ni<4;ni++){
      const int col = n0 + wc*64 + ni*16 + fr;
      float bv = (EPI==0) ? 0.f : bias[col];
      #pragma unroll
      for (int r=0;r<4;r++){
        const int row = m0 + wr*64 + mi*16 + (l>>4)*4 + r;
        float u = acc[mi][ni][r];
        if (EPI==2){ u += bv; u = (u>=0.f)? u : 0.01f*u; }
        else if (EPI==3){ u += bv; }
        if constexpr (std::is_same_v<TC,float>) C[(size_t)row*N + col] = u;
        else                                    C[(size_t)row*N + col] = f2bf(u);
      }
    }
  }
}

// ---------------------------------------------------------------------------
// fp32-compute SGEMM (kept for the two small GEMMs: N=112 and K=48).
// ---------------------------------------------------------------------------
template<typename TA, typename TC, int EPI>
__global__ __launch_bounds__(256)
void sgemm_k(const TA* __restrict__ A, int lda,
             const float* __restrict__ B, int ldb,
             const float* __restrict__ bias, TC* __restrict__ C,
             int M, int N, int K)
{
  constexpr int BM=128, BN=128, BK=8;
  __shared__ float As[BK][BM];
  __shared__ float Bs[BK][BN];
  const int tid = threadIdx.x;
  const int m0 = blockIdx.y*BM, n0 = blockIdx.x*BN;
  const int tx = tid & 15, ty = tid >> 4;
  const int ar = tid >> 1, akq = (tid & 1)*4;
  const int bk = tid >> 5, bn = (tid & 31)*4;
  float acc[8][8];
  #pragma unroll
  for (int i=0;i<8;i++)
    #pragma unroll
    for (int j=0;j<8;j++) acc[i][j]=0.f;

  for (int k0=0;k0<K;k0+=BK){
    if constexpr (std::is_same_v<TA,float>) {
      float4 av = *(const float4*)(A + (size_t)(m0+ar)*lda + k0 + akq);
      As[akq+0][ar]=av.x; As[akq+1][ar]=av.y; As[akq+2][ar]=av.z; As[akq+3][ar]=av.w;
    } else {
      ushort4 av = *(const ushort4*)(A + (size_t)(m0+ar)*lda + k0 + akq);
      As[akq+0][ar]=bf2f(av.x); As[akq+1][ar]=bf2f(av.y);
      As[akq+2][ar]=bf2f(av.z); As[akq+3][ar]=bf2f(av.w);
    }
    const float* Bp = B + (size_t)(k0+bk)*ldb;
    const int bcol = n0 + bn;
    float4 bv;
    if (bcol + 3 < N) {
      bv = *(const float4*)(Bp + bcol);
    } else {
      bv.x = bcol+0<N ? Bp[bcol+0] : 0.f;
      bv.y = bcol+1<N ? Bp[bcol+1] : 0.f;
      bv.z = bcol+2<N ? Bp[bcol+2] : 0.f;
      bv.w = bcol+3<N ? Bp[bcol+3] : 0.f;
    }
    *(float4*)&Bs[bk][bn] = bv;
    __syncthreads();
    #pragma unroll
    for (int k=0;k<BK;k++){
      float a[8], b[8];
      *(float4*)&a[0] = *(const float4*)&As[k][ty*8];
      *(float4*)&a[4] = *(const float4*)&As[k][ty*8+4];
      *(float4*)&b[0] = *(const float4*)&Bs[k][tx*8];
      *(float4*)&b[4] = *(const float4*)&Bs[k][tx*8+4];
      #pragma unroll
      for (int i=0;i<8;i++)
        #pragma unroll
        for (int j=0;j<8;j++)
          acc[i][j] = fmaf(a[i], b[j], acc[i][j]);
    }
    __syncthreads();
  }
  #pragma unroll
  for (int i=0;i<8;i++){
    const size_t row = (size_t)(m0 + ty*8 + i);
    TC* Cp = C + row*(size_t)N;
    #pragma unroll
    for (int j4=0;j4<2;j4++){
      const int col0 = n0 + tx*8 + j4*4;
      if (col0 < N){
        float t[4];
        #pragma unroll
        for (int j=0;j<4;j++){
          float u = acc[i][j4*4+j];
          const int c = col0 + j;
          if (EPI==1){ u += bias[c]; u = (u>20.f)? u : log1pf(__expf(u)); }
          else if (EPI==2){ u += bias[c]; u = (u>=0.f)? u : 0.01f*u; }
          else if (EPI==3){ u += bias[c]; }
          t[j]=u;
        }
        if constexpr (std::is_same_v<TC,float>) {
          float4 v; v.x=t[0]; v.y=t[1]; v.z=t[2]; v.w=t[3];
          *(float4*)(Cp + col0) = v;
        } else {
          ushort4 v; v.x=f2bf(t[0]); v.y=f2bf(t[1]); v.z=f2bf(t[2]); v.w=f2bf(t[3]);
          *(ushort4*)(Cp + col0) = v;
        }
      }
    }
  }
}

// ---------------------------------------------------------------------------
// weight transpose + fp32->bf16:  W [K][N] -> Wt [N][K]
// ---------------------------------------------------------------------------
__global__ __launch_bounds__(256)
void convert_wt_k(const float* __restrict__ W, bf16_t* __restrict__ Wt, int K, int N)
{
  const int idx = blockIdx.x*256 + threadIdx.x;
  if (idx < K*N){
    const int k = idx / N, n = idx % N;
    Wt[(size_t)n*K + k] = f2bf(W[idx]);
  }
}

// x fp32 -> bf16 (vectorized 4-wide)
__global__ __launch_bounds__(256)
void convert_x_k(const float* __restrict__ x, bf16_t* __restrict__ xb, int n4)
{
  const int i = blockIdx.x*256 + threadIdx.x;
  if (i < n4){
    float4 v = *(const float4*)(x + (size_t)i*4);
    ushort4 o; o.x=f2bf(v.x); o.y=f2bf(v.y); o.z=f2bf(v.z); o.w=f2bf(v.w);
    *(ushort4*)(xb + (size_t)i*4) = o;
  }
}

// ---------------------------------------------------------------------------
// Causal depthwise conv1d (width 4, pad-left 3) + bias + silu.
// ---------------------------------------------------------------------------
__global__ __launch_bounds__(256)
void conv_silu_k(const bf16_t* __restrict__ xp, const float* __restrict__ cw,
                 const float* __restrict__ cb, bf16_t* __restrict__ xc)
{
  const int d = blockIdx.x*256 + threadIdx.x;
  const int l = blockIdx.y, b = blockIdx.z;
  float acc = cb[d];
  #pragma unroll
  for (int k=0;k<D_CONV;k++){
    const int ls = l - (D_CONV-1) + k;
    if (ls >= 0)
      acc = fmaf(cw[d*D_CONV+k], bf2f(xp[((size_t)(b*SEQLEN+ls))*D_INNER + d]), acc);
  }
  xc[((size_t)(b*SEQLEN+l))*D_INNER + d] = f2bf(acc * sigmoidf_(acc));
}

// ---------------------------------------------------------------------------
// Selective-scan. Block = 256 thr = 8 d-channels x 32 states. Grid (192, CB).
// Cross-lane reduce over the 32 states via DPP adds (VALU rate, no DS ops):
// xor1,xor2 (quad_perm), xor4 (row_half_mirror), xor8 (row_mirror), then
// row_bcast15 folds row0 into row1 -> lanes 16..31 hold the full 32-sum.
// ---------------------------------------------------------------------------
__global__ __launch_bounds__(256)
void scan_k(const bf16_t* __restrict__ dtb,
            const float*  __restrict__ proj,
            const bf16_t* __restrict__ xc,
            const bf16_t* __restrict__ zb,
            const float*  __restrict__ A_log,
            const float*  __restrict__ Dp,
            bf16_t* __restrict__ yg)
{
  constexpr int TL = 32;
  __shared__ float s_dt[TL][8], s_x[TL][8], s_z[TL][8], s_y[TL][8];
  __shared__ float s_B[TL][32], s_C[TL][32];
  const int tid = threadIdx.x;
  const int n = tid & 31, dl = tid >> 5;
  const int d0 = blockIdx.x * 8, b = blockIdx.y;
  const int d = d0 + dl;
  const float Adn = -expf(A_log[d*D_STATE + n]);
  const float Dd  = Dp[d];
  const int ll = tid >> 3, dd = tid & 7;
  const int lb = tid >> 5;
  float h = 0.f;

  for (int l0 = 0; l0 < SEQLEN; l0 += TL){
    {
      const size_t r = (size_t)b*SEQLEN + l0 + ll;
      s_dt[ll][dd] = bf2f(dtb[r*D_INNER + d0 + dd]);
      s_x [ll][dd] = bf2f(xc [r*D_INNER + d0 + dd]);
      s_z [ll][dd] = bf2f(zb [r*D_INNER + d0 + dd]);
    }
    #pragma unroll
    for (int i=0;i<4;i++){
      const size_t rr = (size_t)b*SEQLEN + l0 + lb + i*8;
      s_B[lb+i*8][n] = proj[rr*(DT_RANK+2*D_STATE) + DT_RANK + n];
      s_C[lb+i*8][n] = proj[rr*(DT_RANK+2*D_STATE) + DT_RANK + D_STATE + n];
    }
    __syncthreads();
    #pragma unroll 8
    for (int t=0;t<TL;t++){
      const float dtl = s_dt[t][dl];
      const float xv  = s_x[t][dl];
      const float dA  = __expf(dtl * Adn);
      h = fmaf(dA, h, (dtl*xv) * s_B[t][n]);
      float y = h * s_C[t][n];
      y = dpp_add<0xB1>(y);    // xor 1 (quad_perm 1,0,3,2)
      y = dpp_add<0x4E>(y);    // xor 2 (quad_perm 2,3,0,1)
      y = dpp_add<0x141>(y);   // xor 4 (row_half_mirror)
      y = dpp_add<0x140>(y);   // xor 8 (row_mirror)
      y = dpp_add<0x142>(y);   // row_bcast15: lanes16-31 += row0 sum
      if (n==16){
        const float zv = s_z[t][dl];
        s_y[t][dl] = (y + xv*Dd) * (zv * sigmoidf_(zv));
      }
    }
    __syncthreads();
    {
      const size_t r = (size_t)b*SEQLEN + l0 + ll;
      yg[r*D_INNER + d0 + dd] = f2bf(s_y[ll][dd]);
    }
    __syncthreads();
  }
}

// ---------------------------------------------------------------------------
extern "C" void kernel_launch(void* const* d_in, const int* in_sizes, int n_in,
                              void* d_out, int out_size, void* d_ws, size_t ws_size,
                              hipStream_t stream) {
  const float* x       = (const float*)d_in[0];
  const float* W_in    = (const float*)d_in[1];
  const float* conv_w  = (const float*)d_in[2];
  const float* conv_b  = (const float*)d_in[3];
  const float* W_xproj = (const float*)d_in[4];
  const float* W_dt    = (const float*)d_in[5];
  const float* b_dt    = (const float*)d_in[6];
  const float* A_log   = (const float*)d_in[7];
  const float* Dp      = (const float*)d_in[8];
  const float* W_out   = (const float*)d_in[9];
  const float* W_ff1   = (const float*)d_in[10];
  const float* b_ff1   = (const float*)d_in[11];
  const float* W_ff2   = (const float*)d_in[12];
  const float* b_ff2   = (const float*)d_in[13];
  float* out = (float*)d_out;

  // ---- transposed-bf16 weight sizes (elements) ----------------------------
  const size_t E_WIN  = (size_t)D_MODEL*2*D_INNER;   // 2.36M  (Wt: [3072][768])
  const size_t E_WOUT = (size_t)D_INNER*D_MODEL;     // 1.18M  (Wt: [768][1536])
  const size_t E_WF1  = (size_t)D_MODEL*N_HIDDEN;    // 1.57M  (Wt: [2048][768])
  const size_t E_WF2  = (size_t)N_HIDDEN*ACTION_BINS;// 0.52M  (Wt: [256][2048])
  const size_t WT_BYTES = 2*(E_WIN + E_WOUT + E_WF1 + E_WF2);  // 11.3 MB

  // ---- adaptive batch chunking --------------------------------------------
  const size_t SZ16_1 = (size_t)SEQLEN * D_INNER * 2;             // 12,582,912
  const size_t PROJ_1 = (size_t)SEQLEN * (DT_RANK+2*D_STATE) * 4; //  1,835,008
  const size_t PER_B  = 4*SZ16_1 + PROJ_1;                        // 52,166,656
  int CB = 0;
  for (int cb = BATCH; cb >= 1; cb >>= 1)
    if ((size_t)cb * PER_B + WT_BYTES <= ws_size) { CB = cb; break; }
  if (CB == 0) return;

  const size_t SZ16 = (size_t)CB * SZ16_1;
  char* wsb = (char*)d_ws;
  bf16_t* A_pre = (bf16_t*)wsb;                 // -> DT after conv
  bf16_t* Z     = (bf16_t*)(wsb +   SZ16);      // -> H1 after scan
  bf16_t* XC    = (bf16_t*)(wsb + 2*SZ16);      // -> H2 (+PROJ+YG) after GEMM6
  float*  PROJ  = (float*) (wsb + 3*SZ16);
  bf16_t* YG    = (bf16_t*)(wsb + 3*SZ16 + (size_t)CB*PROJ_1);
  bf16_t* DT    = A_pre;
  bf16_t* H1    = Z;
  bf16_t* H2    = XC;
  bf16_t* XB    = YG;        // x-as-bf16 lives in YG slot (dead before scan)

  bf16_t* WT    = (bf16_t*)(wsb + (size_t)CB * PER_B);
  bf16_t* WT_in  = WT;
  bf16_t* WT_out = WT_in  + E_WIN;
  bf16_t* WT_ff1 = WT_out + E_WOUT;
  bf16_t* WT_ff2 = WT_ff1 + E_WF1;

  const int Mc = CB * SEQLEN;
  const int nchunks = BATCH / CB;
  dim3 blk(256);

  // ---- once per call: weights -> bf16, transposed -------------------------
  convert_wt_k<<<dim3((int)((E_WIN +255)/256)), blk, 0, stream>>>(W_in,  WT_in,  D_MODEL, 2*D_INNER);
  convert_wt_k<<<dim3((int)((E_WOUT+255)/256)), blk, 0, stream>>>(W_out, WT_out, D_INNER, D_MODEL);
  convert_wt_k<<<dim3((int)((E_WF1 +255)/256)), blk, 0, stream>>>(W_ff1, WT_ff1, D_MODEL, N_HIDDEN);
  convert_wt_k<<<dim3((int)((E_WF2 +255)/256)), blk, 0, stream>>>(W_ff2, WT_ff2, N_HIDDEN, ACTION_BINS);

  for (int c = 0; c < nchunks; ++c) {
    const float* xc_in = x   + (size_t)c*Mc*D_MODEL;
    float*       out_c = out + (size_t)c*Mc*ACTION_BINS;

    // 0) XB = bf16(x chunk)    (lives in YG region; dead before scan writes YG)
    convert_x_k<<<dim3((Mc*D_MODEL/4 + 255)/256), blk, 0, stream>>>(xc_in, XB, Mc*D_MODEL/4);

    // 1a) A_pre = XB @ W_in[:, :1536]      (MFMA)
    mgemm_k<bf16_t,0><<<dim3(D_INNER/128, Mc/128), blk, 0, stream>>>(
        XB, D_MODEL, WT_in, nullptr, A_pre, Mc, D_INNER, D_MODEL);
    // 1b) Z = XB @ W_in[:, 1536:]          (MFMA)
    mgemm_k<bf16_t,0><<<dim3(D_INNER/128, Mc/128), blk, 0, stream>>>(
        XB, D_MODEL, WT_in + (size_t)D_INNER*D_MODEL, nullptr, Z, Mc, D_INNER, D_MODEL);

    // 2) XC = silu(causal_conv(A_pre) + conv_b)
    conv_silu_k<<<dim3(D_INNER/256, SEQLEN, CB), blk, 0, stream>>>(A_pre, conv_w, conv_b, XC);

    // 3) PROJ = XC @ W_xproj               [Mc,1536]@[1536,112] fp32 (N=112 edge)
    sgemm_k<bf16_t,float,0><<<dim3(1, Mc/128), blk, 0, stream>>>(
        XC, D_INNER, W_xproj, DT_RANK+2*D_STATE, nullptr, PROJ, Mc, DT_RANK+2*D_STATE, D_INNER);

    // 4) DT = softplus(PROJ[:, :48] @ W_dt + b_dt)   [Mc,48]@[48,1536] fp32 (K=48)
    sgemm_k<float,bf16_t,1><<<dim3(D_INNER/128, Mc/128), blk, 0, stream>>>(
        PROJ, DT_RANK+2*D_STATE, W_dt, D_INNER, b_dt, DT, Mc, D_INNER, DT_RANK);

    // 5) selective scan + skip + gate -> YG (overwrites XB; XB dead)
    scan_k<<<dim3(D_INNER/8, CB), blk, 0, stream>>>(DT, PROJ, XC, Z, A_log, Dp, YG);

    // 6) H1 = YG @ W_out                   (MFMA)
    mgemm_k<bf16_t,0><<<dim3(D_MODEL/128, Mc/128), blk, 0, stream>>>(
        YG, D_INNER, WT_out, nullptr, H1, Mc, D_MODEL, D_INNER);

    // 7) H2 = leaky_relu(H1 @ W_ff1 + b_ff1)   (MFMA)
    mgemm_k<bf16_t,2><<<dim3(N_HIDDEN/128, Mc/128), blk, 0, stream>>>(
        H1, D_MODEL, WT_ff1, b_ff1, H2, Mc, N_HIDDEN, D_MODEL);

    // 8) out = H2 @ W_ff2 + b_ff2              (MFMA, fp32 out)
    mgemm_k<float,3><<<dim3(ACTION_BINS/128, Mc/128), blk, 0, stream>>>(
        H2, N_HIDDEN, WT_ff2, b_ff2, out_c, Mc, ACTION_BINS, N_HIDDEN);
  }
}